// Round 4
// baseline (125.975 us; speedup 1.0000x reference)
//
#include <hip/hip_runtime.h>

constexpr int NRES = 8192;
constexpr int NIN  = 64;
constexpr int NOUT = 32;
constexpr float DT_OVER_TAU = 0.1f / 10.0f;  // 0.01

typedef float float4v __attribute__((ext_vector_type(4)));

// One block per reservoir row (proven round-2 streaming shape), readout fused
// into the epilogue via 32 atomicAdds per block.
//   state      = W[row,:]@r + W_in[row,:]@u + W_fb[row,:]@y
//   r_new      = r[row] + (dt/tau)*(tanh(state) - r[row])   (register-only)
//   out[o]    += W_out[o,row] * r_new                        (atomic)
__global__ __launch_bounds__(256) void reservoir_fused_kernel(
    const float* __restrict__ W,
    const float* __restrict__ W_in,
    const float* __restrict__ W_fb,
    const float* __restrict__ W_out,
    const float* __restrict__ u,
    const float* __restrict__ r,
    const float* __restrict__ yprev,
    float* __restrict__ out)
{
    const int row = blockIdx.x;
    const int t   = threadIdx.x;
    const float* wrow = W + (size_t)row * NRES;

    float acc = 0.0f;
#pragma unroll
    for (int j = 0; j < 8; ++j) {
        const int c = (j * 256 + t) * 4;              // 16B/lane, coalesced
        // W is streamed exactly once -> non-temporal, keep L1/L2 for r & W_out
        float4v wv = __builtin_nontemporal_load(
                         reinterpret_cast<const float4v*>(wrow + c));
        float4v rv = *reinterpret_cast<const float4v*>(r + c);
        acc += wv[0] * rv[0] + wv[1] * rv[1] + wv[2] * rv[2] + wv[3] * rv[3];
    }
    // tiny input/feedback dots folded into the same block reduction
    if (t < NIN)  acc += W_in[row * NIN + t] * u[t];
    if (t < NOUT) acc += W_fb[row * NOUT + t] * yprev[t];

    // wave(64) reduce, then cross-wave via LDS
#pragma unroll
    for (int off = 32; off > 0; off >>= 1)
        acc += __shfl_down(acc, off, 64);

    __shared__ float partial[4];
    __shared__ float srnew;
    const int wid  = t >> 6;
    const int lane = t & 63;
    if (lane == 0) partial[wid] = acc;
    __syncthreads();

    if (t == 0) {
        float state = partial[0] + partial[1] + partial[2] + partial[3];
        float ri = r[row];
        srnew = ri + DT_OVER_TAU * (tanhf(state) - ri);
    }
    __syncthreads();

    if (t < NOUT)                                     // W_out column: L2-resident
        atomicAdd(&out[t], W_out[(size_t)t * NRES + row] * srnew);
}

extern "C" void kernel_launch(void* const* d_in, const int* in_sizes, int n_in,
                              void* d_out, int out_size, void* d_ws, size_t ws_size,
                              hipStream_t stream) {
    // setup_inputs order: input_signal, W, W_in, W_fb, W_out, r, out_prev
    const float* u     = (const float*)d_in[0];
    const float* W     = (const float*)d_in[1];
    const float* W_in  = (const float*)d_in[2];
    const float* W_fb  = (const float*)d_in[3];
    const float* W_out = (const float*)d_in[4];
    const float* r     = (const float*)d_in[5];
    const float* yprev = (const float*)d_in[6];

    float* out = (float*)d_out;

    hipMemsetAsync(out, 0, NOUT * sizeof(float), stream);  // in-graph, re-zeroes每replay
    reservoir_fused_kernel<<<NRES, 256, 0, stream>>>(
        W, W_in, W_fb, W_out, u, r, yprev, out);
}

// Round 5
// 51.804 us; speedup vs baseline: 2.4318x; 2.4318x over previous
//
#include <hip/hip_runtime.h>

constexpr int NRES = 8192;
constexpr int NIN  = 64;
constexpr int NOUT = 32;
constexpr float DT_OVER_TAU = 0.1f / 10.0f;  // 0.01

typedef float float4v __attribute__((ext_vector_type(4)));

// Kernel A — exact round-2 streaming shape (proven ~6.5 TB/s):
// one block per reservoir row, writes r_new[row] to ws.
__global__ __launch_bounds__(256) void reservoir_state_kernel(
    const float* __restrict__ W,
    const float* __restrict__ W_in,
    const float* __restrict__ W_fb,
    const float* __restrict__ u,
    const float* __restrict__ r,
    const float* __restrict__ y,
    float* __restrict__ r_new)
{
    const int row = blockIdx.x;
    const int t   = threadIdx.x;
    const float* wrow = W + (size_t)row * NRES;

    float acc = 0.0f;
#pragma unroll
    for (int j = 0; j < 8; ++j) {
        const int c = (j * 256 + t) * 4;              // 16B/lane, coalesced
        float4v wv = *reinterpret_cast<const float4v*>(wrow + c);
        float4v rv = *reinterpret_cast<const float4v*>(r + c);
        acc += wv[0] * rv[0] + wv[1] * rv[1] + wv[2] * rv[2] + wv[3] * rv[3];
    }
    if (t < NIN)  acc += W_in[row * NIN + t] * u[t];
    if (t < NOUT) acc += W_fb[row * NOUT + t] * y[t];

#pragma unroll
    for (int off = 32; off > 0; off >>= 1)
        acc += __shfl_down(acc, off, 64);

    __shared__ float partial[4];
    const int wid  = t >> 6;
    const int lane = t & 63;
    if (lane == 0) partial[wid] = acc;
    __syncthreads();

    if (t == 0) {
        float state = partial[0] + partial[1] + partial[2] + partial[3];
        float ri = r[row];
        r_new[row] = ri + DT_OVER_TAU * (tanhf(state) - ri);
    }
}

// Kernel B — low-latency readout: 256 blocks, block b handles output row
// (b>>3), chunk (b&7) of 1024 elems; one atomicAdd per block (8 per address).
__global__ __launch_bounds__(256) void readout_kernel(
    const float* __restrict__ W_out,
    const float* __restrict__ r_new,
    float* __restrict__ out)
{
    const int o     = blockIdx.x >> 3;        // 0..31
    const int chunk = blockIdx.x & 7;         // 0..7
    const int t     = threadIdx.x;
    const int base  = chunk * 1024 + t * 4;

    const float* wrow = W_out + (size_t)o * NRES;
    float4v wv = *reinterpret_cast<const float4v*>(wrow + base);
    float4v rv = *reinterpret_cast<const float4v*>(r_new + base);
    float acc = wv[0] * rv[0] + wv[1] * rv[1] + wv[2] * rv[2] + wv[3] * rv[3];

#pragma unroll
    for (int off = 32; off > 0; off >>= 1)
        acc += __shfl_down(acc, off, 64);

    __shared__ float partial[4];
    const int wid  = t >> 6;
    const int lane = t & 63;
    if (lane == 0) partial[wid] = acc;
    __syncthreads();

    if (t == 0)
        atomicAdd(&out[o], partial[0] + partial[1] + partial[2] + partial[3]);
}

extern "C" void kernel_launch(void* const* d_in, const int* in_sizes, int n_in,
                              void* d_out, int out_size, void* d_ws, size_t ws_size,
                              hipStream_t stream) {
    // setup_inputs order: input_signal, W, W_in, W_fb, W_out, r, out_prev
    const float* u     = (const float*)d_in[0];
    const float* W     = (const float*)d_in[1];
    const float* W_in  = (const float*)d_in[2];
    const float* W_fb  = (const float*)d_in[3];
    const float* W_out = (const float*)d_in[4];
    const float* r     = (const float*)d_in[5];
    const float* y     = (const float*)d_in[6];

    float* r_new = (float*)d_ws;              // 8192 floats = 32 KB scratch
    float* out   = (float*)d_out;

    hipMemsetAsync(out, 0, NOUT * sizeof(float), stream);  // in-graph re-zero
    reservoir_state_kernel<<<NRES, 256, 0, stream>>>(W, W_in, W_fb, u, r, y, r_new);
    readout_kernel<<<NOUT * 8, 256, 0, stream>>>(W_out, r_new, out);
}

// Round 7
// 46.347 us; speedup vs baseline: 2.7181x; 1.1177x over previous
//
#include <hip/hip_runtime.h>

constexpr int NRES = 8192;
constexpr int NIN  = 64;
constexpr int NOUT = 32;
constexpr float DT_OVER_TAU = 0.1f / 10.0f;  // 0.01

typedef float float4v __attribute__((ext_vector_type(4)));

// One block per reservoir row:
//   state      = W[row,:]@r + W_in[row,:]@u + W_fb[row,:]@y
//   r_new[row] = r[row] + (dt/tau) * (tanh(state) - r[row])
// Proven streaming shape: 8192 blocks x 256 threads, float4 coalesced,
// ~6.7 TB/s on the 268 MB W read (round 2: 46.35 us total).
__global__ __launch_bounds__(256) void reservoir_state_kernel(
    const float* __restrict__ W,
    const float* __restrict__ W_in,
    const float* __restrict__ W_fb,
    const float* __restrict__ u,
    const float* __restrict__ r,
    const float* __restrict__ y,
    float* __restrict__ r_new)
{
    const int row = blockIdx.x;
    const int t   = threadIdx.x;
    const float* wrow = W + (size_t)row * NRES;

    float acc = 0.0f;
#pragma unroll
    for (int j = 0; j < 8; ++j) {
        const int c = (j * 256 + t) * 4;              // 16B/lane, coalesced
        float4v wv = *reinterpret_cast<const float4v*>(wrow + c);
        float4v rv = *reinterpret_cast<const float4v*>(r + c);
        acc += wv[0] * rv[0] + wv[1] * rv[1] + wv[2] * rv[2] + wv[3] * rv[3];
    }
    // Tiny input/feedback dots, folded into the same block reduction.
    if (t < NIN)  acc += W_in[row * NIN + t] * u[t];
    if (t < NOUT) acc += W_fb[row * NOUT + t] * y[t];

    // wave(64) reduce, then LDS across the 4 waves
#pragma unroll
    for (int off = 32; off > 0; off >>= 1)
        acc += __shfl_down(acc, off, 64);

    __shared__ float partial[4];
    const int wid  = t >> 6;
    const int lane = t & 63;
    if (lane == 0) partial[wid] = acc;
    __syncthreads();

    if (t == 0) {
        float state = partial[0] + partial[1] + partial[2] + partial[3];
        float ri = r[row];
        r_new[row] = ri + DT_OVER_TAU * (tanhf(state) - ri);
    }
}

// One block per output row: out[o] = W_out[o,:] @ r_new
__global__ __launch_bounds__(256) void readout_kernel(
    const float* __restrict__ W_out,
    const float* __restrict__ r_new,
    float* __restrict__ out)
{
    const int row = blockIdx.x;   // 0..31
    const int t   = threadIdx.x;
    const float* wrow = W_out + (size_t)row * NRES;

    float acc = 0.0f;
#pragma unroll
    for (int j = 0; j < 8; ++j) {
        const int c = (j * 256 + t) * 4;
        float4v wv = *reinterpret_cast<const float4v*>(wrow + c);
        float4v rv = *reinterpret_cast<const float4v*>(r_new + c);
        acc += wv[0] * rv[0] + wv[1] * rv[1] + wv[2] * rv[2] + wv[3] * rv[3];
    }

#pragma unroll
    for (int off = 32; off > 0; off >>= 1)
        acc += __shfl_down(acc, off, 64);

    __shared__ float partial[4];
    const int wid  = t >> 6;
    const int lane = t & 63;
    if (lane == 0) partial[wid] = acc;
    __syncthreads();

    if (t == 0)
        out[row] = partial[0] + partial[1] + partial[2] + partial[3];
}

extern "C" void kernel_launch(void* const* d_in, const int* in_sizes, int n_in,
                              void* d_out, int out_size, void* d_ws, size_t ws_size,
                              hipStream_t stream) {
    // setup_inputs order: input_signal, W, W_in, W_fb, W_out, r, out_prev
    const float* u     = (const float*)d_in[0];
    const float* W     = (const float*)d_in[1];
    const float* W_in  = (const float*)d_in[2];
    const float* W_fb  = (const float*)d_in[3];
    const float* W_out = (const float*)d_in[4];
    const float* r     = (const float*)d_in[5];
    const float* y     = (const float*)d_in[6];

    float* r_new = (float*)d_ws;                 // 8192 floats = 32 KB scratch
    float* out   = (float*)d_out;

    reservoir_state_kernel<<<NRES, 256, 0, stream>>>(W, W_in, W_fb, u, r, y, r_new);
    readout_kernel<<<NOUT, 256, 0, stream>>>(W_out, r_new, out);
}